// Round 6
// baseline (158.568 us; speedup 1.0000x reference)
//
#include <hip/hip_runtime.h>
#include <math.h>

// Problem constants (match reference)
#define BB 4096
#define LL 128
#define DD 64

// Round-6 structure: ZERO mid-kernel barriers.
//  - one wave = one full side (128 rows); block = 128 threads = {side a, side b}
//  - all reductions in-wave (shfl_xor butterflies); ids/scores in a wave-private
//    LDS slice (lockstep wave64 -> no __syncthreads, only wave_barrier() fences)
//  - q needs all rows -> scores re-gather mu (R4<->R5 showed refetch is
//    time-neutral; it's L2-hot)
//  - id and mask packed into one int: bit31 set = masked row
//  - single __syncthreads at the end for the a/b cosine exchange
__global__ __launch_bounds__(128, 6) void softmax_attn_cos_kernel(
    const int* __restrict__ ids_a, const int* __restrict__ mask_a,
    const int* __restrict__ ids_b, const int* __restrict__ mask_b,
    const float* __restrict__ mu_table, const float* __restrict__ feat_table,
    float* __restrict__ out)
{
    __shared__ int   s_idm[2][LL];    // id | (masked ? 0x80000000 : 0)
    __shared__ float s_sc[2][LL];     // scores -> exp weights
    __shared__ float s_mean[2][DD];   // per-side mean vectors

    const int tid  = threadIdx.x;
    const int lane = tid & 63;
    const int wave = tid >> 6;        // 0 = side a, 1 = side b
    const int grp  = lane >> 4;       // 0..3: row subgroup within an iteration
    const int c4   = lane & 15;       // float4 column index
    const int b    = blockIdx.x;

    const int* idp = wave ? ids_b  : ids_a;
    const int* mp  = wave ? mask_b : mask_a;

    // ---- load ids + masks (2 per lane, coalesced), pack, count nm in-wave ----
    const int id0 = idp[b * LL + lane];
    const int id1 = idp[b * LL + lane + 64];
    const int m0  = mp[b * LL + lane];
    const int m1  = mp[b * LL + lane + 64];
    s_idm[wave][lane]      = id0 | (m0 ? 0 : (int)0x80000000);
    s_idm[wave][lane + 64] = id1 | (m1 ? 0 : (int)0x80000000);
    __builtin_amdgcn_wave_barrier();   // order LDS writes before cross-lane reads

    float mv = (float)(m0 + m1);
    #pragma unroll
    for (int off = 32; off; off >>= 1) mv += __shfl_xor(mv, off, 64);
    const float denom = fmaxf(mv, 1.0f);
    const bool  allm  = (mv < 0.5f);

    // ---- pass A: masked mu gather, q = masked mean (in registers) ----
    float4 qp = make_float4(0.f, 0.f, 0.f, 0.f);
    #pragma unroll
    for (int it = 0; it < 32; ++it) {
        const int im = s_idm[wave][it * 4 + grp];
        if (im >= 0) {
            const float4 f = ((const float4*)(mu_table + (size_t)im * DD))[c4];
            qp.x += f.x; qp.y += f.y; qp.z += f.z; qp.w += f.w;
        }
    }
    #pragma unroll
    for (int off = 16; off <= 32; off <<= 1) {   // sum the 4 row-groups
        qp.x += __shfl_xor(qp.x, off, 64);
        qp.y += __shfl_xor(qp.y, off, 64);
        qp.z += __shfl_xor(qp.z, off, 64);
        qp.w += __shfl_xor(qp.w, off, 64);
    }
    const float rd = 1.0f / denom;
    const float4 q4 = make_float4(qp.x * rd, qp.y * rd, qp.z * rd, qp.w * rd);

    // ---- pass B: scores (mu re-gather, L2-hot) ----
    #pragma unroll
    for (int it = 0; it < 32; ++it) {
        const int r  = it * 4 + grp;
        const int im = s_idm[wave][r];
        float sc = -1e9f;
        if (im >= 0) {
            const float4 f = ((const float4*)(mu_table + (size_t)im * DD))[c4];
            sc = f.x * q4.x + f.y * q4.y + f.z * q4.z + f.w * q4.w;
            #pragma unroll
            for (int off = 1; off <= 8; off <<= 1)
                sc += __shfl_xor(sc, off, 64);   // reduce within 16-lane group
        }
        if (c4 == 0) s_sc[wave][r] = sc;
    }
    __builtin_amdgcn_wave_barrier();

    // ---- softmax over 128 scores, fully in-wave ----
    const float s1 = s_sc[wave][lane], s2 = s_sc[wave][lane + 64];
    float mx = fmaxf(s1, s2);
    #pragma unroll
    for (int off = 32; off; off >>= 1) mx = fmaxf(mx, __shfl_xor(mx, off, 64));
    const float e1 = expf(s1 - mx), e2 = expf(s2 - mx);
    s_sc[wave][lane] = e1; s_sc[wave][lane + 64] = e2;
    __builtin_amdgcn_wave_barrier();
    float sm = e1 + e2;
    #pragma unroll
    for (int off = 32; off; off >>= 1) sm += __shfl_xor(sm, off, 64);
    const float inv = 1.0f / sm;

    // ---- pass C: attn-weighted feat gather ----
    float4 op = make_float4(0.f, 0.f, 0.f, 0.f);
    #pragma unroll
    for (int it = 0; it < 32; ++it) {
        const int r  = it * 4 + grp;
        const int im = s_idm[wave][r];
        if (allm || im >= 0) {
            const int   id = im & 0x7fffffff;
            const float w  = s_sc[wave][r];
            const float4 f = ((const float4*)(feat_table + (size_t)id * DD))[c4];
            op.x = fmaf(f.x, w, op.x); op.y = fmaf(f.y, w, op.y);
            op.z = fmaf(f.z, w, op.z); op.w = fmaf(f.w, w, op.w);
        }
    }
    #pragma unroll
    for (int off = 16; off <= 32; off <<= 1) {
        op.x += __shfl_xor(op.x, off, 64);
        op.y += __shfl_xor(op.y, off, 64);
        op.z += __shfl_xor(op.z, off, 64);
        op.w += __shfl_xor(op.w, off, 64);
    }
    if (lane < 16) {   // grp==0, c4==lane: holds the full column sum
        float4 o;
        o.x = op.x * inv; o.y = op.y * inv; o.z = op.z * inv; o.w = op.w * inv;
        ((float4*)&s_mean[wave][0])[c4] = o;
    }

    // ---- the ONLY block barrier: exchange means, cosine (wave 0) ----
    __syncthreads();
    if (tid < 64) {
        const float a = s_mean[0][tid], c = s_mean[1][tid];
        float dt = a * c, na = a * a, nb = c * c;
        #pragma unroll
        for (int off = 32; off; off >>= 1) {
            dt += __shfl_xor(dt, off, 64);
            na += __shfl_xor(na, off, 64);
            nb += __shfl_xor(nb, off, 64);
        }
        if (tid == 0) {
            const float dn = fmaxf(sqrtf(na), 1e-8f) * fmaxf(sqrtf(nb), 1e-8f);
            out[b] = 5.0f * dt / dn;
        }
    }
}

extern "C" void kernel_launch(void* const* d_in, const int* in_sizes, int n_in,
                              void* d_out, int out_size, void* d_ws, size_t ws_size,
                              hipStream_t stream) {
    const int*   ids_a  = (const int*)d_in[0];
    const int*   mask_a = (const int*)d_in[1];
    const int*   ids_b  = (const int*)d_in[2];
    const int*   mask_b = (const int*)d_in[3];
    const float* mu     = (const float*)d_in[4];
    const float* feat   = (const float*)d_in[5];
    float* out = (float*)d_out;

    softmax_attn_cos_kernel<<<BB, 128, 0, stream>>>(
        ids_a, mask_a, ids_b, mask_b, mu, feat, out);
}

// Round 7
// 136.844 us; speedup vs baseline: 1.1588x; 1.1588x over previous
//
#include <hip/hip_runtime.h>
#include <hip/hip_fp16.h>
#include <math.h>

// Problem constants (match reference)
#define BB 4096
#define LL 128
#define DD 64
#define VV 50257
#define TAB_ELEMS (VV * DD)   // 3,216,448 per table

// ---------------------------------------------------------------------------
// Kernel 1: stream-convert both fp32 tables to fp16 in workspace (each launch;
// d_ws is re-poisoned by the harness). 38 MB streamed ~ 6 us.
// ---------------------------------------------------------------------------
__global__ __launch_bounds__(256) void convert_tables_kernel(
    const float* __restrict__ mu, const float* __restrict__ feat,
    __half* __restrict__ out_mu, __half* __restrict__ out_feat)
{
    const int n4 = TAB_ELEMS / 4;   // 804112 float4-groups per table
    for (int i = blockIdx.x * blockDim.x + threadIdx.x; i < n4;
         i += gridDim.x * blockDim.x) {
        const float4 m = ((const float4*)mu)[i];
        const float4 f = ((const float4*)feat)[i];
        union { __half2 h[2]; uint2 u; } pm, pf;
        pm.h[0] = __floats2half2_rn(m.x, m.y);
        pm.h[1] = __floats2half2_rn(m.z, m.w);
        pf.h[0] = __floats2half2_rn(f.x, f.y);
        pf.h[1] = __floats2half2_rn(f.z, f.w);
        ((uint2*)out_mu)[i]   = pm.u;
        ((uint2*)out_feat)[i] = pf.u;
    }
}

// ---------------------------------------------------------------------------
// Kernel 2: the proven round-4 structure, with 8 B/lane fp16 gathers
// (row = 128 B = 1 cache line). All arithmetic in fp32 after conversion.
// ---------------------------------------------------------------------------
__device__ __forceinline__ float4 load_row4(const __half* __restrict__ tab,
                                            int id, int c4) {
    const uint2 raw = ((const uint2*)(tab + (size_t)id * DD))[c4];
    const float2 f01 = __half22float2(*(const __half2*)&raw.x);
    const float2 f23 = __half22float2(*(const __half2*)&raw.y);
    return make_float4(f01.x, f01.y, f23.x, f23.y);
}

__global__ __launch_bounds__(256, 8) void softmax_attn_cos_kernel(
    const int* __restrict__ ids_a, const int* __restrict__ mask_a,
    const int* __restrict__ ids_b, const int* __restrict__ mask_b,
    const __half* __restrict__ mu_table, const __half* __restrict__ feat_table,
    float* __restrict__ out)
{
    __shared__ int    s_ids[2][LL];
    __shared__ float  s_msk[2][LL];
    __shared__ float4 s_q[2][16];
    __shared__ float4 s_qp[2][2][16];
    __shared__ float  s_sc[2][LL];
    __shared__ float4 s_op[2][2][16];
    __shared__ float  s_mean[2][DD];
    __shared__ float  s_sum[2];
    __shared__ int    s_nm[2];

    const int tid  = threadIdx.x;
    const int lane = tid & 63;
    const int wave = tid >> 6;        // 0..3
    const int side = wave >> 1;       // 0: a, 1: b
    const int wsub = wave & 1;        // which half of the 128 rows
    const int grp  = lane >> 4;       // 0..3 row subgroup
    const int c4   = lane & 15;       // 4-column group index
    const int b    = blockIdx.x;

    // ---- phase 1: ids + masks for both sides ----
    {
        const int si = tid >> 7;
        const int l  = tid & 127;
        const int* idp = si ? ids_b  : ids_a;
        const int* mp  = si ? mask_b : mask_a;
        s_ids[si][l] = idp[b * LL + l];
        s_msk[si][l] = (float)mp[b * LL + l];
    }
    __syncthreads();

    // ---- phase 2: masked mu accumulation, 4 rows / iteration ----
    {
        float4 qp = make_float4(0.f, 0.f, 0.f, 0.f);
        #pragma unroll
        for (int it = 0; it < 16; ++it) {
            const int r = wsub * 64 + it * 4 + grp;
            if (s_msk[side][r] > 0.5f) {
                const float4 f = load_row4(mu_table, s_ids[side][r], c4);
                qp.x += f.x; qp.y += f.y; qp.z += f.z; qp.w += f.w;
            }
        }
        #pragma unroll
        for (int off = 16; off <= 32; off <<= 1) {   // sum the 4 row-groups
            qp.x += __shfl_xor(qp.x, off, 64);
            qp.y += __shfl_xor(qp.y, off, 64);
            qp.z += __shfl_xor(qp.z, off, 64);
            qp.w += __shfl_xor(qp.w, off, 64);
        }
        if (lane < 16) s_qp[side][wsub][c4] = qp;
    }
    __syncthreads();

    // ---- q = masked mean + nm count (waves 0/1, one per side) ----
    if (tid < 128) {
        const int si = tid >> 6;
        const int dd = tid & 63;
        float mv = s_msk[si][dd] + s_msk[si][dd + 64];
        #pragma unroll
        for (int off = 32; off; off >>= 1) mv += __shfl_xor(mv, off, 64);
        if (dd == 0) s_nm[si] = (int)(mv + 0.5f);
        const float denom = fmaxf(mv, 1.0f);
        if (dd < 16) {
            float4 q0 = s_qp[si][0][dd], q1 = s_qp[si][1][dd];
            float4 q;
            q.x = (q0.x + q1.x) / denom; q.y = (q0.y + q1.y) / denom;
            q.z = (q0.z + q1.z) / denom; q.w = (q0.w + q1.w) / denom;
            s_q[si][dd] = q;
        }
    }
    __syncthreads();

    // ---- phase 3: scores, mu re-gather (L2-hot, mask-skipped) ----
    {
        const float4 q4 = s_q[side][c4];
        #pragma unroll
        for (int it = 0; it < 16; ++it) {
            const int r = wsub * 64 + it * 4 + grp;
            float sc = -1e9f;
            if (s_msk[side][r] > 0.5f) {
                const float4 f = load_row4(mu_table, s_ids[side][r], c4);
                sc = f.x * q4.x + f.y * q4.y + f.z * q4.z + f.w * q4.w;
                #pragma unroll
                for (int off = 1; off <= 8; off <<= 1)
                    sc += __shfl_xor(sc, off, 64);   // reduce within 16-lane group
            }
            if (c4 == 0) s_sc[side][r] = sc;
        }
    }
    __syncthreads();

    // ---- phase 4: softmax per side (waves with wsub==0) ----
    if (wsub == 0) {
        const float s1 = s_sc[side][lane], s2 = s_sc[side][lane + 64];
        float mx = fmaxf(s1, s2);
        #pragma unroll
        for (int off = 32; off; off >>= 1) mx = fmaxf(mx, __shfl_xor(mx, off, 64));
        const float e1 = expf(s1 - mx), e2 = expf(s2 - mx);
        s_sc[side][lane] = e1; s_sc[side][lane + 64] = e2;
        float sm = e1 + e2;
        #pragma unroll
        for (int off = 32; off; off >>= 1) sm += __shfl_xor(sm, off, 64);
        if (lane == 0) s_sum[side] = sm;
    }
    __syncthreads();

    // ---- phase 5: attn-weighted feat, mask-skip ----
    {
        const bool allm = (s_nm[side] == 0);
        float4 op = make_float4(0.f, 0.f, 0.f, 0.f);
        #pragma unroll
        for (int it = 0; it < 16; ++it) {
            const int r = wsub * 64 + it * 4 + grp;
            if (allm || s_msk[side][r] > 0.5f) {
                const float w  = s_sc[side][r];
                const float4 f = load_row4(feat_table, s_ids[side][r], c4);
                op.x = fmaf(f.x, w, op.x); op.y = fmaf(f.y, w, op.y);
                op.z = fmaf(f.z, w, op.z); op.w = fmaf(f.w, w, op.w);
            }
        }
        #pragma unroll
        for (int off = 16; off <= 32; off <<= 1) {
            op.x += __shfl_xor(op.x, off, 64);
            op.y += __shfl_xor(op.y, off, 64);
            op.z += __shfl_xor(op.z, off, 64);
            op.w += __shfl_xor(op.w, off, 64);
        }
        if (lane < 16) s_op[side][wsub][c4] = op;
    }
    __syncthreads();

    // ---- combine halves -> mean vectors ----
    if (tid < 32) {
        const int si = tid >> 4, cc = tid & 15;
        const float inv = 1.0f / s_sum[si];
        float4 o0 = s_op[si][0][cc], o1 = s_op[si][1][cc];
        float4 o;
        o.x = (o0.x + o1.x) * inv; o.y = (o0.y + o1.y) * inv;
        o.z = (o0.z + o1.z) * inv; o.w = (o0.w + o1.w) * inv;
        ((float4*)&s_mean[si][0])[cc] = o;
    }
    __syncthreads();

    // ---- cosine similarity * 5 (wave 0) ----
    if (tid < 64) {
        const float a = s_mean[0][tid], c = s_mean[1][tid];
        float dt = a * c, na = a * a, nb = c * c;
        #pragma unroll
        for (int off = 32; off; off >>= 1) {
            dt += __shfl_xor(dt, off, 64);
            na += __shfl_xor(na, off, 64);
            nb += __shfl_xor(nb, off, 64);
        }
        if (tid == 0) {
            const float denom = fmaxf(sqrtf(na), 1e-8f) * fmaxf(sqrtf(nb), 1e-8f);
            out[b] = 5.0f * dt / denom;
        }
    }
}

extern "C" void kernel_launch(void* const* d_in, const int* in_sizes, int n_in,
                              void* d_out, int out_size, void* d_ws, size_t ws_size,
                              hipStream_t stream) {
    const int*   ids_a  = (const int*)d_in[0];
    const int*   mask_a = (const int*)d_in[1];
    const int*   ids_b  = (const int*)d_in[2];
    const int*   mask_b = (const int*)d_in[3];
    const float* mu     = (const float*)d_in[4];
    const float* feat   = (const float*)d_in[5];
    float* out = (float*)d_out;

    __half* ws_mu   = (__half*)d_ws;
    __half* ws_feat = ws_mu + TAB_ELEMS;   // needs 2*TAB_ELEMS*2 B ~ 12.3 MB of ws

    convert_tables_kernel<<<1024, 256, 0, stream>>>(mu, feat, ws_mu, ws_feat);
    softmax_attn_cos_kernel<<<BB, 256, 0, stream>>>(
        ids_a, mask_a, ids_b, mask_b, ws_mu, ws_feat, out);
}